// Round 21
// baseline (162.425 us; speedup 1.0000x reference)
//
#include <hip/hip_runtime.h>

#define NN 50000
#define NE 800000
#define C 128
#define H 16

typedef unsigned int u32;
typedef unsigned short u16;
typedef __fp16 h2 __attribute__((ext_vector_type(2)));
typedef __fp16 half8 __attribute__((ext_vector_type(8)));
typedef float f32x4 __attribute__((ext_vector_type(4)));

__device__ __forceinline__ h2 as_h2(u32 v) {
  union { u32 u; h2 h; } c; c.u = v; return c.h;
}
__device__ __forceinline__ u32 as_u32(h2 h) {
  union { u32 u; h2 h; } c; c.h = h; return c.u;
}
__device__ __forceinline__ half8 as_half8(uint4 v) {
  union { uint4 u; half8 h; } c; c.u = v; return c.h;
}
#define PK(a, b) __builtin_amdgcn_cvt_pkrtz((a), (b))

// ---------- silu + 7 cubic B-spline bases, closed form, NAMED outputs ----------
__device__ __forceinline__ void feat8s(float x, float& s, float& g0, float& g1,
                                       float& g2, float& g3, float& g4, float& g5,
                                       float& g6) {
  s = x / (1.f + __expf(-x));
  float t = (x + 2.5f) * 2.0f;
  float cf = floorf(t);
  int c = (int)cf;
  float u = t - cf;
  float u2 = u * u, u3 = u2 * u;
  const float k6 = 1.f / 6.f;
  float P0 = u3 * k6;
  float P1 = (1.f + 3.f * u + 3.f * u2 - 3.f * u3) * k6;
  float P2 = (4.f - 6.f * u2 + 3.f * u3) * k6;
  float om = 1.f - u;
  float P3 = om * om * om * k6;
  bool valid = (t >= 0.f) && (t < 10.f);
#define SPJ(G, J)                                   \
  {                                                 \
    float b = 0.f;                                  \
    b = (c == (J)) ? P0 : b;                        \
    b = (c == (J) + 1) ? P1 : b;                    \
    b = (c == (J) + 2) ? P2 : b;                    \
    b = (c == (J) + 3) ? P3 : b;                    \
    G = valid ? b : 0.f;                            \
  }
  SPJ(g0, 0) SPJ(g1, 1) SPJ(g2, 2) SPJ(g3, 3) SPJ(g4, 4) SPJ(g5, 5) SPJ(g6, 6)
#undef SPJ
}

__device__ __forceinline__ u16 f2bf(float v) {
  u32 b = __float_as_uint(v);
  return (u16)((b + 0x7fffu + ((b >> 16) & 1u)) >> 16);  // RNE
}
__device__ __forceinline__ u16 f2h(float v) {
  union { __fp16 h; u16 u; } c; c.h = (__fp16)v; return c.u;
}
__device__ __forceinline__ float blo(u32 v) { return __uint_as_float(v << 16); }
__device__ __forceinline__ float bhi(u32 v) { return __uint_as_float(v & 0xffff0000u); }

// build a half8 A-fragment from one feat8s evaluation
__device__ __forceinline__ uint4 featfrag(float x) {
  float t0, t1, t2, t3, t4, t5, t6, t7;
  feat8s(x, t0, t1, t2, t3, t4, t5, t6, t7);
  uint4 r;
  r.x = as_u32(PK(t0, t1));
  r.y = as_u32(PK(t2, t3));
  r.z = as_u32(PK(t4, t5));
  r.w = as_u32(PK(t6, t7));
  return r;
}

// ---------- prep_w: f16 W + f16 KAN weights + zero cnt (196 blocks) ----------
__global__ void prep_w(const float* __restrict__ W,
                       const float* __restrict__ bw0, const float* __restrict__ sw0,
                       const float* __restrict__ sc0,
                       const float* __restrict__ bw1, const float* __restrict__ sw1,
                       const float* __restrict__ sc1,
                       u32* __restrict__ W16, u16* __restrict__ p0h,
                       u16* __restrict__ p1h, int* __restrict__ cnt) {
  int i = blockIdx.x * blockDim.x + threadIdx.x;
  if (i < NN) cnt[i] = 0;
  if (i < C * C / 2) {  // W row-major, packed f16 pairs along k
    int o = i >> 6, kp = i & 63;
    W16[i] = (u32)f2h(W[o * C + kp * 2]) | ((u32)f2h(W[o * C + kp * 2 + 1]) << 16);
  }
  if (i < H * C * 8) {  // p0h[hidden][k=f*8+j]
    int of = i >> 3, j = i & 7;
    float v = (j == 0) ? bw0[of] : sw0[of * 7 + (j - 1)] * sc0[of];
    p0h[i] = f2h(v);
  }
  if (i < C * H * 8) {  // p1h[out][k=j*8+t]
    int of = i >> 3, j = i & 7;
    float v = (j == 0) ? bw1[of] : sw1[of * 7 + (j - 1)] * sc1[of];
    p1h[i] = f2h(v);
  }
}

// ---------- count + slot capture (u16 slots) ----------
__global__ void count_kernel(const int* __restrict__ dst, int* __restrict__ cnt,
                             u16* __restrict__ slot) {
  int e = blockIdx.x * blockDim.x + threadIdx.x;
  if (e < NE) slot[e] = (u16)atomicAdd(&cnt[dst[e]], 1);
}

// ---------- scan1 ----------
__global__ void scan1(const int* __restrict__ cnt, int* __restrict__ excl,
                      int* __restrict__ bsums, int n) {
  int i = blockIdx.x * 256 + threadIdx.x;
  int v = (i < n) ? cnt[i] : 0;
  int lane = threadIdx.x & 63, wid = threadIdx.x >> 6;
  int s = v;
#pragma unroll
  for (int o = 1; o < 64; o <<= 1) {
    int t = __shfl_up(s, o, 64);
    if (lane >= o) s += t;
  }
  __shared__ int wsum[4];
  if (lane == 63) wsum[wid] = s;
  __syncthreads();
  int woff = 0;
  for (int w = 0; w < wid; ++w) woff += wsum[w];
  if (i < n) excl[i] = woff + s - v;
  if (threadIdx.x == 255) bsums[blockIdx.x] = woff + s;
}

// ---------- scan3 ----------
__global__ void scan3(const int* __restrict__ excl, const int* __restrict__ bsums,
                      const int* __restrict__ cnt, int* __restrict__ row_start,
                      float* __restrict__ dinv, int n, int nb) {
  __shared__ int red[256];
  const int t = threadIdx.x;
  red[t] = (t < nb && t < (int)blockIdx.x) ? bsums[t] : 0;
  __syncthreads();
#pragma unroll
  for (int s = 128; s > 0; s >>= 1) {
    if (t < s) red[t] += red[t + s];
    __syncthreads();
  }
  const int boff = red[0];
  const int i = blockIdx.x * 256 + t;
  if (i < n) {
    row_start[i] = excl[i] + boff;
    dinv[i] = rsqrtf((float)(cnt[i] + 1));
  }
  if (blockIdx.x == 0 && t == 0) row_start[n] = NE;
}

// ---------- xs_prep ----------
__global__ void xs_prep(const float* __restrict__ x, const float* __restrict__ dinv,
                        u32* __restrict__ xs) {
  int i = blockIdx.x * blockDim.x + threadIdx.x;
  if (i < NN * C / 4) {
    int n = i >> 5;
    float dv = dinv[n];
    float4 v = *(const float4*)&x[(size_t)i * 4];
    u32 lo = (u32)f2bf(v.x * dv) | ((u32)f2bf(v.y * dv) << 16);
    u32 hi = (u32)f2bf(v.z * dv) | ((u32)f2bf(v.w * dv) << 16);
    *(uint2*)&xs[(size_t)i * 2] = make_uint2(lo, hi);
  }
}

// ---------- CSR fill: atomic-free 2B scatter ----------
__global__ void fill_kernel(const int* __restrict__ src, const int* __restrict__ dst,
                            const u16* __restrict__ slot,
                            const int* __restrict__ row_start, u16* __restrict__ csr) {
  int e = blockIdx.x * blockDim.x + threadIdx.x;
  if (e < NE) csr[row_start[dst[e]] + (int)slot[e]] = (u16)src[e];
}

// ---------- aggregation (u16 csr stream) ----------
__global__ __launch_bounds__(256, 8) void agg_kernel(
    const u32* __restrict__ xs, const u16* __restrict__ csr,
    const int* __restrict__ row_start, const float* __restrict__ dinv,
    u32* __restrict__ ax16) {
  const int l = threadIdx.x & 63;
  const int node = blockIdx.x * 4 + (threadIdx.x >> 6);
  const int e0 = row_start[node], e1 = row_start[node + 1];
  const float dn = dinv[node];
  const u32 vs = xs[(size_t)node * 64 + l];
  float a0 = blo(vs), a1 = bhi(vs);
  int e = e0;
  for (; e + 8 <= e1; e += 8) {
    const int s0 = csr[e], s1 = csr[e + 1], s2 = csr[e + 2], s3 = csr[e + 3];
    const int s4 = csr[e + 4], s5 = csr[e + 5], s6 = csr[e + 6], s7 = csr[e + 7];
    const u32 v0 = xs[(size_t)s0 * 64 + l];
    const u32 v1 = xs[(size_t)s1 * 64 + l];
    const u32 v2 = xs[(size_t)s2 * 64 + l];
    const u32 v3 = xs[(size_t)s3 * 64 + l];
    const u32 v4 = xs[(size_t)s4 * 64 + l];
    const u32 v5 = xs[(size_t)s5 * 64 + l];
    const u32 v6 = xs[(size_t)s6 * 64 + l];
    const u32 v7 = xs[(size_t)s7 * 64 + l];
    a0 += blo(v0); a1 += bhi(v0);
    a0 += blo(v1); a1 += bhi(v1);
    a0 += blo(v2); a1 += bhi(v2);
    a0 += blo(v3); a1 += bhi(v3);
    a0 += blo(v4); a1 += bhi(v4);
    a0 += blo(v5); a1 += bhi(v5);
    a0 += blo(v6); a1 += bhi(v6);
    a0 += blo(v7); a1 += bhi(v7);
  }
  for (; e < e1; ++e) {
    const u32 v = xs[(size_t)csr[e] * 64 + l];
    a0 += blo(v);
    a1 += bhi(v);
  }
  a0 *= dn;
  a1 *= dn;
  ax16[(size_t)node * 64 + l] = (u32)f2h(a0) | ((u32)f2h(a1) << 16);
}

// ---------- gemmkan v3: wave-pair split (2x TLP; r19/r20: scheduler won't ILP) ----------
// 512 threads = 8 waves = 4 tiles x 2 halves. Per tile, halves split:
//   Phase A: t in [4h,4h+4)   K0: s in [16h,16h+16)   K1: t in [4h,4h+4).
// hT natural layout [node][col] (write/read both ~2-way conflict-free);
// K0 partials reduced via hidT (write / sync / add / sync).
__global__ __launch_bounds__(512) void gemmkan(
    const u32* __restrict__ ax16, const u32* __restrict__ W16,
    const float* __restrict__ bias, const u16* __restrict__ p0h,
    const u16* __restrict__ p1h, float* __restrict__ out) {
  __shared__ float hT[4][16][132];
  __shared__ float hidT[4][16][17];
  const int wv = threadIdx.x >> 6;   // 0..7
  const int tile = wv >> 1;          // 0..3
  const int half = wv & 1;           // 0,1
  const int l = threadIdx.x & 63;
  int m0 = (blockIdx.x * 4 + tile) * 16;
  const bool valid = m0 < NN;
  if (!valid) m0 = 0;                // clamp for safe loads; stores predicated
  const int rc = l & 15, kb = l >> 4;
  // ---- Phase A: GCN GEMM, halves split t ----
  {
    uint4 a[4];
#pragma unroll
    for (int s = 0; s < 4; ++s)
      a[s] = *(const uint4*)&ax16[(size_t)(m0 + rc) * 64 + s * 16 + kb * 4];
    f32x4 acc[4];
#pragma unroll
    for (int tt = 0; tt < 4; ++tt) acc[tt] = (f32x4){0.f, 0.f, 0.f, 0.f};
#pragma unroll
    for (int tt = 0; tt < 4; ++tt) {
      const int t = half * 4 + tt;
#pragma unroll
      for (int s = 0; s < 4; ++s) {
        uint4 b = *(const uint4*)&W16[(size_t)(t * 16 + rc) * 64 + s * 16 + kb * 4];
        acc[tt] = __builtin_amdgcn_mfma_f32_16x16x32_f16(as_half8(a[s]), as_half8(b),
                                                         acc[tt], 0, 0, 0);
      }
    }
#pragma unroll
    for (int tt = 0; tt < 4; ++tt) {
      const int t = half * 4 + tt;
      const float bo = bias[t * 16 + rc];
#pragma unroll
      for (int r = 0; r < 4; ++r) {
        hT[tile][kb * 4 + r][t * 16 + rc] = acc[tt][r] + bo;
      }
    }
  }
  __syncthreads();
  // ---- K0: halves split s; 2 alternating accumulators ----
  f32x4 accA = (f32x4){0.f, 0.f, 0.f, 0.f};
  f32x4 accB = (f32x4){0.f, 0.f, 0.f, 0.f};
#pragma unroll
  for (int g = 0; g < 4; ++g) {
    const int s0 = half * 16 + g * 4;
    float h0 = hT[tile][rc][(s0 + 0) * 4 + kb];
    float h1 = hT[tile][rc][(s0 + 1) * 4 + kb];
    float h2v = hT[tile][rc][(s0 + 2) * 4 + kb];
    float h3 = hT[tile][rc][(s0 + 3) * 4 + kb];
    uint4 f0 = featfrag(h0);
    uint4 f1 = featfrag(h1);
    uint4 f2 = featfrag(h2v);
    uint4 f3 = featfrag(h3);
    uint4 b0 = *(const uint4*)&p0h[rc * 1024 + (s0 + 0) * 32 + kb * 8];
    uint4 b1 = *(const uint4*)&p0h[rc * 1024 + (s0 + 1) * 32 + kb * 8];
    uint4 b2 = *(const uint4*)&p0h[rc * 1024 + (s0 + 2) * 32 + kb * 8];
    uint4 b3 = *(const uint4*)&p0h[rc * 1024 + (s0 + 3) * 32 + kb * 8];
    accA = __builtin_amdgcn_mfma_f32_16x16x32_f16(as_half8(f0), as_half8(b0), accA, 0, 0, 0);
    accB = __builtin_amdgcn_mfma_f32_16x16x32_f16(as_half8(f1), as_half8(b1), accB, 0, 0, 0);
    accA = __builtin_amdgcn_mfma_f32_16x16x32_f16(as_half8(f2), as_half8(b2), accA, 0, 0, 0);
    accB = __builtin_amdgcn_mfma_f32_16x16x32_f16(as_half8(f3), as_half8(b3), accB, 0, 0, 0);
  }
  f32x4 part = accA + accB;
  // ---- cross-wave reduce of hid partials (transposed store) ----
  if (half == 0) {
#pragma unroll
    for (int r = 0; r < 4; ++r) hidT[tile][kb * 4 + r][rc] = part[r];
  }
  __syncthreads();
  if (half == 1) {
#pragma unroll
    for (int r = 0; r < 4; ++r) hidT[tile][kb * 4 + r][rc] += part[r];
  }
  __syncthreads();
  // ---- K1 A-fragments (both halves compute; cheap) ----
  uint4 af0 = featfrag(hidT[tile][rc][0 * 4 + kb]);
  uint4 af1 = featfrag(hidT[tile][rc][1 * 4 + kb]);
  uint4 af2 = featfrag(hidT[tile][rc][2 * 4 + kb]);
  uint4 af3 = featfrag(hidT[tile][rc][3 * 4 + kb]);
  // ---- K1: halves split t ----
  f32x4 acc1[4];
#pragma unroll
  for (int tt = 0; tt < 4; ++tt) acc1[tt] = (f32x4){0.f, 0.f, 0.f, 0.f};
#pragma unroll
  for (int tt = 0; tt < 4; ++tt) {
    const int t = half * 4 + tt;
    const u16* prow = &p1h[(size_t)(t * 16 + rc) * 128];
    uint4 b0 = *(const uint4*)&prow[0 * 32 + kb * 8];
    uint4 b1 = *(const uint4*)&prow[1 * 32 + kb * 8];
    uint4 b2 = *(const uint4*)&prow[2 * 32 + kb * 8];
    uint4 b3 = *(const uint4*)&prow[3 * 32 + kb * 8];
    acc1[tt] = __builtin_amdgcn_mfma_f32_16x16x32_f16(as_half8(af0), as_half8(b0), acc1[tt], 0, 0, 0);
    acc1[tt] = __builtin_amdgcn_mfma_f32_16x16x32_f16(as_half8(af1), as_half8(b1), acc1[tt], 0, 0, 0);
    acc1[tt] = __builtin_amdgcn_mfma_f32_16x16x32_f16(as_half8(af2), as_half8(b2), acc1[tt], 0, 0, 0);
    acc1[tt] = __builtin_amdgcn_mfma_f32_16x16x32_f16(as_half8(af3), as_half8(b3), acc1[tt], 0, 0, 0);
  }
  if (valid) {
#pragma unroll
    for (int tt = 0; tt < 4; ++tt) {
      const int t = half * 4 + tt;
#pragma unroll
      for (int r = 0; r < 4; ++r) {
        out[(size_t)(m0 + kb * 4 + r) * C + t * 16 + rc] = acc1[tt][r];
      }
    }
  }
}

extern "C" void kernel_launch(void* const* d_in, const int* in_sizes, int n_in,
                              void* d_out, int out_size, void* d_ws, size_t ws_size,
                              hipStream_t stream) {
  const float* x   = (const float*)d_in[0];
  const int*   ei  = (const int*)d_in[1];
  const float* gw  = (const float*)d_in[2];
  const float* gb  = (const float*)d_in[3];
  const float* bw0 = (const float*)d_in[4];
  const float* sw0 = (const float*)d_in[5];
  const float* sc0 = (const float*)d_in[6];
  const float* bw1 = (const float*)d_in[7];
  const float* sw1 = (const float*)d_in[8];
  const float* sc1 = (const float*)d_in[9];
  float* out = (float*)d_out;

  char* p = (char*)d_ws;
  u32* W16 = (u32*)p;         p += C * C * 2;
  u16* p0h = (u16*)p;         p += H * C * 8 * 2;
  u16* p1h = (u16*)p;         p += C * H * 8 * 2;
  float* dinv = (float*)p;    p += NN * 4;
  int* cnt = (int*)p;         p += NN * 4;
  int* excl = (int*)p;        p += NN * 4;
  int* bsums = (int*)p;       p += 256 * 4;
  int* row_start = (int*)p;   p += (NN + 4) * 4;
  u16* slot = (u16*)p;        p += (size_t)NE * 2;       // 1.6 MB
  u16* csr = (u16*)p;         p += (size_t)NE * 2;       // 1.6 MB
  p = (char*)(((size_t)p + 15) & ~(size_t)15);
  u32* xs = (u32*)p;          p += (size_t)NN * C * 2;   // 12.8 MB
  u32* ax16 = (u32*)p;        p += (size_t)NN * C * 2;   // 12.8 MB

  const int* src = ei;
  const int* dst = ei + NE;

  prep_w<<<196, 256, 0, stream>>>(gw, bw0, sw0, sc0, bw1, sw1, sc1, W16, p0h, p1h, cnt);
  count_kernel<<<(NE + 255) / 256, 256, 0, stream>>>(dst, cnt, slot);
  scan1<<<196, 256, 0, stream>>>(cnt, excl, bsums, NN);
  scan3<<<196, 256, 0, stream>>>(excl, bsums, cnt, row_start, dinv, NN, 196);
  xs_prep<<<(NN * C / 4 + 255) / 256, 256, 0, stream>>>(x, dinv, xs);
  fill_kernel<<<(NE + 255) / 256, 256, 0, stream>>>(src, dst, slot, row_start, csr);
  agg_kernel<<<NN / 4, 256, 0, stream>>>(xs, csr, row_start, dinv, ax16);
  gemmkan<<<(NN / 64 + 1), 512, 0, stream>>>(ax16, W16, gb, p0h, p1h, out);
}

// Round 22
// 159.512 us; speedup vs baseline: 1.0183x; 1.0183x over previous
//
#include <hip/hip_runtime.h>

#define NN 50000
#define NE 800000
#define C 128
#define H 16

typedef unsigned int u32;
typedef unsigned short u16;
typedef __fp16 h2 __attribute__((ext_vector_type(2)));
typedef __fp16 half8 __attribute__((ext_vector_type(8)));
typedef float f32x4 __attribute__((ext_vector_type(4)));

__device__ __forceinline__ h2 as_h2(u32 v) {
  union { u32 u; h2 h; } c; c.u = v; return c.h;
}
__device__ __forceinline__ u32 as_u32(h2 h) {
  union { u32 u; h2 h; } c; c.h = h; return c.u;
}
__device__ __forceinline__ half8 as_half8(uint4 v) {
  union { uint4 u; half8 h; } c; c.u = v; return c.h;
}
#define PK(a, b) __builtin_amdgcn_cvt_pkrtz((a), (b))

// ---------- silu + 7 cubic B-spline bases, closed form, NAMED outputs ----------
// silu via v_rcp (1 ulp) instead of IEEE-div expansion (~6 instr cheaper).
__device__ __forceinline__ void feat8s(float x, float& s, float& g0, float& g1,
                                       float& g2, float& g3, float& g4, float& g5,
                                       float& g6) {
  float e = __expf(-x);
  s = x * __builtin_amdgcn_rcpf(1.f + e);
  float t = (x + 2.5f) * 2.0f;
  float cf = floorf(t);
  int c = (int)cf;
  float u = t - cf;
  float u2 = u * u, u3 = u2 * u;
  const float k6 = 1.f / 6.f;
  float P0 = u3 * k6;
  float P1 = (1.f + 3.f * u + 3.f * u2 - 3.f * u3) * k6;
  float P2 = (4.f - 6.f * u2 + 3.f * u3) * k6;
  float om = 1.f - u;
  float P3 = om * om * om * k6;
  bool valid = (t >= 0.f) && (t < 10.f);
#define SPJ(G, J)                                   \
  {                                                 \
    float b = 0.f;                                  \
    b = (c == (J)) ? P0 : b;                        \
    b = (c == (J) + 1) ? P1 : b;                    \
    b = (c == (J) + 2) ? P2 : b;                    \
    b = (c == (J) + 3) ? P3 : b;                    \
    G = valid ? b : 0.f;                            \
  }
  SPJ(g0, 0) SPJ(g1, 1) SPJ(g2, 2) SPJ(g3, 3) SPJ(g4, 4) SPJ(g5, 5) SPJ(g6, 6)
#undef SPJ
}

__device__ __forceinline__ u16 f2bf(float v) {
  u32 b = __float_as_uint(v);
  return (u16)((b + 0x7fffu + ((b >> 16) & 1u)) >> 16);  // RNE
}
__device__ __forceinline__ u16 f2h(float v) {
  union { __fp16 h; u16 u; } c; c.h = (__fp16)v; return c.u;
}
__device__ __forceinline__ float blo(u32 v) { return __uint_as_float(v << 16); }
__device__ __forceinline__ float bhi(u32 v) { return __uint_as_float(v & 0xffff0000u); }

// build a half8 A-fragment from one feat8s evaluation
__device__ __forceinline__ uint4 featfrag(float x) {
  float t0, t1, t2, t3, t4, t5, t6, t7;
  feat8s(x, t0, t1, t2, t3, t4, t5, t6, t7);
  uint4 r;
  r.x = as_u32(PK(t0, t1));
  r.y = as_u32(PK(t2, t3));
  r.z = as_u32(PK(t4, t5));
  r.w = as_u32(PK(t6, t7));
  return r;
}

// ---------- prep_w: f16 W + f16 KAN weights + zero cnt (196 blocks) ----------
__global__ void prep_w(const float* __restrict__ W,
                       const float* __restrict__ bw0, const float* __restrict__ sw0,
                       const float* __restrict__ sc0,
                       const float* __restrict__ bw1, const float* __restrict__ sw1,
                       const float* __restrict__ sc1,
                       u32* __restrict__ W16, u16* __restrict__ p0h,
                       u16* __restrict__ p1h, int* __restrict__ cnt) {
  int i = blockIdx.x * blockDim.x + threadIdx.x;
  if (i < NN) cnt[i] = 0;
  if (i < C * C / 2) {  // W row-major, packed f16 pairs along k
    int o = i >> 6, kp = i & 63;
    W16[i] = (u32)f2h(W[o * C + kp * 2]) | ((u32)f2h(W[o * C + kp * 2 + 1]) << 16);
  }
  if (i < H * C * 8) {  // p0h[hidden][k=f*8+j]
    int of = i >> 3, j = i & 7;
    float v = (j == 0) ? bw0[of] : sw0[of * 7 + (j - 1)] * sc0[of];
    p0h[i] = f2h(v);
  }
  if (i < C * H * 8) {  // p1h[out][k=j*8+t]
    int of = i >> 3, j = i & 7;
    float v = (j == 0) ? bw1[of] : sw1[of * 7 + (j - 1)] * sc1[of];
    p1h[i] = f2h(v);
  }
}

// ---------- count + slot capture (u16 slots) ----------
__global__ void count_kernel(const int* __restrict__ dst, int* __restrict__ cnt,
                             u16* __restrict__ slot) {
  int e = blockIdx.x * blockDim.x + threadIdx.x;
  if (e < NE) slot[e] = (u16)atomicAdd(&cnt[dst[e]], 1);
}

// ---------- scan1 ----------
__global__ void scan1(const int* __restrict__ cnt, int* __restrict__ excl,
                      int* __restrict__ bsums, int n) {
  int i = blockIdx.x * 256 + threadIdx.x;
  int v = (i < n) ? cnt[i] : 0;
  int lane = threadIdx.x & 63, wid = threadIdx.x >> 6;
  int s = v;
#pragma unroll
  for (int o = 1; o < 64; o <<= 1) {
    int t = __shfl_up(s, o, 64);
    if (lane >= o) s += t;
  }
  __shared__ int wsum[4];
  if (lane == 63) wsum[wid] = s;
  __syncthreads();
  int woff = 0;
  for (int w = 0; w < wid; ++w) woff += wsum[w];
  if (i < n) excl[i] = woff + s - v;
  if (threadIdx.x == 255) bsums[blockIdx.x] = woff + s;
}

// ---------- scan3 ----------
__global__ void scan3(const int* __restrict__ excl, const int* __restrict__ bsums,
                      const int* __restrict__ cnt, int* __restrict__ row_start,
                      float* __restrict__ dinv, int n, int nb) {
  __shared__ int red[256];
  const int t = threadIdx.x;
  red[t] = (t < nb && t < (int)blockIdx.x) ? bsums[t] : 0;
  __syncthreads();
#pragma unroll
  for (int s = 128; s > 0; s >>= 1) {
    if (t < s) red[t] += red[t + s];
    __syncthreads();
  }
  const int boff = red[0];
  const int i = blockIdx.x * 256 + t;
  if (i < n) {
    row_start[i] = excl[i] + boff;
    dinv[i] = rsqrtf((float)(cnt[i] + 1));
  }
  if (blockIdx.x == 0 && t == 0) row_start[n] = NE;
}

// ---------- xs_prep ----------
__global__ void xs_prep(const float* __restrict__ x, const float* __restrict__ dinv,
                        u32* __restrict__ xs) {
  int i = blockIdx.x * blockDim.x + threadIdx.x;
  if (i < NN * C / 4) {
    int n = i >> 5;
    float dv = dinv[n];
    float4 v = *(const float4*)&x[(size_t)i * 4];
    u32 lo = (u32)f2bf(v.x * dv) | ((u32)f2bf(v.y * dv) << 16);
    u32 hi = (u32)f2bf(v.z * dv) | ((u32)f2bf(v.w * dv) << 16);
    *(uint2*)&xs[(size_t)i * 2] = make_uint2(lo, hi);
  }
}

// ---------- CSR fill: atomic-free 2B scatter ----------
__global__ void fill_kernel(const int* __restrict__ src, const int* __restrict__ dst,
                            const u16* __restrict__ slot,
                            const int* __restrict__ row_start, u16* __restrict__ csr) {
  int e = blockIdx.x * blockDim.x + threadIdx.x;
  if (e < NE) csr[row_start[dst[e]] + (int)slot[e]] = (u16)src[e];
}

// ---------- aggregation (u16 csr stream) ----------
__global__ __launch_bounds__(256, 8) void agg_kernel(
    const u32* __restrict__ xs, const u16* __restrict__ csr,
    const int* __restrict__ row_start, const float* __restrict__ dinv,
    u32* __restrict__ ax16) {
  const int l = threadIdx.x & 63;
  const int node = blockIdx.x * 4 + (threadIdx.x >> 6);
  const int e0 = row_start[node], e1 = row_start[node + 1];
  const float dn = dinv[node];
  const u32 vs = xs[(size_t)node * 64 + l];
  float a0 = blo(vs), a1 = bhi(vs);
  int e = e0;
  for (; e + 8 <= e1; e += 8) {
    const int s0 = csr[e], s1 = csr[e + 1], s2 = csr[e + 2], s3 = csr[e + 3];
    const int s4 = csr[e + 4], s5 = csr[e + 5], s6 = csr[e + 6], s7 = csr[e + 7];
    const u32 v0 = xs[(size_t)s0 * 64 + l];
    const u32 v1 = xs[(size_t)s1 * 64 + l];
    const u32 v2 = xs[(size_t)s2 * 64 + l];
    const u32 v3 = xs[(size_t)s3 * 64 + l];
    const u32 v4 = xs[(size_t)s4 * 64 + l];
    const u32 v5 = xs[(size_t)s5 * 64 + l];
    const u32 v6 = xs[(size_t)s6 * 64 + l];
    const u32 v7 = xs[(size_t)s7 * 64 + l];
    a0 += blo(v0); a1 += bhi(v0);
    a0 += blo(v1); a1 += bhi(v1);
    a0 += blo(v2); a1 += bhi(v2);
    a0 += blo(v3); a1 += bhi(v3);
    a0 += blo(v4); a1 += bhi(v4);
    a0 += blo(v5); a1 += bhi(v5);
    a0 += blo(v6); a1 += bhi(v6);
    a0 += blo(v7); a1 += bhi(v7);
  }
  for (; e < e1; ++e) {
    const u32 v = xs[(size_t)csr[e] * 64 + l];
    a0 += blo(v);
    a1 += bhi(v);
  }
  a0 *= dn;
  a1 *= dn;
  ax16[(size_t)node * 64 + l] = (u32)f2h(a0) | ((u32)f2h(a1) << 16);
}

// ---------- gemmkan v4: LOOPED (not unrolled) hot phases to fit I$ ----------
// r19-r21 lesson: fully-unrolled body ~40KB > 32KB I$; wave-count and ILP
// changes were both null because instruction FETCH was the cap. Loops shrink
// code to a few KB. Structure = r20 (1 wave/tile, permuted hT, dual accum).
__global__ __launch_bounds__(256, 3) void gemmkan(
    const u32* __restrict__ ax16, const u32* __restrict__ W16,
    const float* __restrict__ bias, const u16* __restrict__ p0h,
    const u16* __restrict__ p1h, float* __restrict__ out) {
  __shared__ float hT[4][16][132];
  __shared__ float hidT[4][16][17];
  const int wv = threadIdx.x >> 6;
  const int l = threadIdx.x & 63;
  const int m0 = (blockIdx.x * 4 + wv) * 16;
  if (m0 >= NN) return;
  const int rc = l & 15, kb = l >> 4;
  // ---- Phase A: GCN GEMM (looped over t) ----
  {
    uint4 a[4];
#pragma unroll
    for (int s = 0; s < 4; ++s)
      a[s] = *(const uint4*)&ax16[(size_t)(m0 + rc) * 64 + s * 16 + kb * 4];
    const int pbase = (rc & 3) * 32 + (rc >> 2);
#pragma unroll 1
    for (int t = 0; t < 8; ++t) {
      f32x4 acc = (f32x4){0.f, 0.f, 0.f, 0.f};
      const u32* wrow = &W16[(size_t)(t * 16 + rc) * 64 + kb * 4];
#pragma unroll
      for (int s = 0; s < 4; ++s) {
        uint4 b = *(const uint4*)&wrow[s * 16];
        acc = __builtin_amdgcn_mfma_f32_16x16x32_f16(as_half8(a[s]), as_half8(b),
                                                     acc, 0, 0, 0);
      }
      const float bo = bias[t * 16 + rc];
#pragma unroll
      for (int r = 0; r < 4; ++r) {
        hT[wv][kb * 4 + r][pbase + t * 4] = acc[r] + bo;
      }
    }
  }
  __builtin_amdgcn_s_waitcnt(0);  // wave-local LDS ordering (r17-proven)
  // ---- K0: looped groups of 4 (1 b128 LDS read, 4 featfrags, 4 MFMA) ----
  const float* hrow = &hT[wv][rc][kb * 32];
  const u16* pb = &p0h[rc * 1024 + kb * 8];
  f32x4 accA = (f32x4){0.f, 0.f, 0.f, 0.f};
  f32x4 accB = (f32x4){0.f, 0.f, 0.f, 0.f};
#pragma unroll 1
  for (int g = 0; g < 8; ++g) {
    float4 hv = *(const float4*)&hrow[g * 4];
    uint4 f0 = featfrag(hv.x);
    uint4 f1 = featfrag(hv.y);
    uint4 f2 = featfrag(hv.z);
    uint4 f3 = featfrag(hv.w);
    uint4 b0 = *(const uint4*)&pb[(g * 4 + 0) * 32];
    uint4 b1 = *(const uint4*)&pb[(g * 4 + 1) * 32];
    uint4 b2 = *(const uint4*)&pb[(g * 4 + 2) * 32];
    uint4 b3 = *(const uint4*)&pb[(g * 4 + 3) * 32];
    accA = __builtin_amdgcn_mfma_f32_16x16x32_f16(as_half8(f0), as_half8(b0), accA, 0, 0, 0);
    accB = __builtin_amdgcn_mfma_f32_16x16x32_f16(as_half8(f1), as_half8(b1), accB, 0, 0, 0);
    accA = __builtin_amdgcn_mfma_f32_16x16x32_f16(as_half8(f2), as_half8(b2), accA, 0, 0, 0);
    accB = __builtin_amdgcn_mfma_f32_16x16x32_f16(as_half8(f3), as_half8(b3), accB, 0, 0, 0);
  }
  f32x4 acc0 = accA + accB;
  // ---- transpose hid within the wave ----
#pragma unroll
  for (int r = 0; r < 4; ++r) hidT[wv][kb * 4 + r][rc] = acc0[r];
  __builtin_amdgcn_s_waitcnt(0);
  // ---- K1 A-fragments (4 independent chains) ----
  uint4 af0 = featfrag(hidT[wv][rc][0 * 4 + kb]);
  uint4 af1 = featfrag(hidT[wv][rc][1 * 4 + kb]);
  uint4 af2 = featfrag(hidT[wv][rc][2 * 4 + kb]);
  uint4 af3 = featfrag(hidT[wv][rc][3 * 4 + kb]);
  // ---- K1: looped over 8 output tiles ----
#pragma unroll 1
  for (int t = 0; t < 8; ++t) {
    const u16* prow = &p1h[(size_t)(t * 16 + rc) * 128];
    uint4 b0 = *(const uint4*)&prow[0 * 32 + kb * 8];
    uint4 b1 = *(const uint4*)&prow[1 * 32 + kb * 8];
    uint4 b2 = *(const uint4*)&prow[2 * 32 + kb * 8];
    uint4 b3 = *(const uint4*)&prow[3 * 32 + kb * 8];
    f32x4 acc1 = (f32x4){0.f, 0.f, 0.f, 0.f};
    acc1 = __builtin_amdgcn_mfma_f32_16x16x32_f16(as_half8(af0), as_half8(b0), acc1, 0, 0, 0);
    acc1 = __builtin_amdgcn_mfma_f32_16x16x32_f16(as_half8(af1), as_half8(b1), acc1, 0, 0, 0);
    acc1 = __builtin_amdgcn_mfma_f32_16x16x32_f16(as_half8(af2), as_half8(b2), acc1, 0, 0, 0);
    acc1 = __builtin_amdgcn_mfma_f32_16x16x32_f16(as_half8(af3), as_half8(b3), acc1, 0, 0, 0);
#pragma unroll
    for (int r = 0; r < 4; ++r) {
      out[(size_t)(m0 + kb * 4 + r) * C + t * 16 + rc] = acc1[r];
    }
  }
}

extern "C" void kernel_launch(void* const* d_in, const int* in_sizes, int n_in,
                              void* d_out, int out_size, void* d_ws, size_t ws_size,
                              hipStream_t stream) {
  const float* x   = (const float*)d_in[0];
  const int*   ei  = (const int*)d_in[1];
  const float* gw  = (const float*)d_in[2];
  const float* gb  = (const float*)d_in[3];
  const float* bw0 = (const float*)d_in[4];
  const float* sw0 = (const float*)d_in[5];
  const float* sc0 = (const float*)d_in[6];
  const float* bw1 = (const float*)d_in[7];
  const float* sw1 = (const float*)d_in[8];
  const float* sc1 = (const float*)d_in[9];
  float* out = (float*)d_out;

  char* p = (char*)d_ws;
  u32* W16 = (u32*)p;         p += C * C * 2;
  u16* p0h = (u16*)p;         p += H * C * 8 * 2;
  u16* p1h = (u16*)p;         p += C * H * 8 * 2;
  float* dinv = (float*)p;    p += NN * 4;
  int* cnt = (int*)p;         p += NN * 4;
  int* excl = (int*)p;        p += NN * 4;
  int* bsums = (int*)p;       p += 256 * 4;
  int* row_start = (int*)p;   p += (NN + 4) * 4;
  u16* slot = (u16*)p;        p += (size_t)NE * 2;       // 1.6 MB
  u16* csr = (u16*)p;         p += (size_t)NE * 2;       // 1.6 MB
  p = (char*)(((size_t)p + 15) & ~(size_t)15);
  u32* xs = (u32*)p;          p += (size_t)NN * C * 2;   // 12.8 MB
  u32* ax16 = (u32*)p;        p += (size_t)NN * C * 2;   // 12.8 MB

  const int* src = ei;
  const int* dst = ei + NE;

  prep_w<<<196, 256, 0, stream>>>(gw, bw0, sw0, sc0, bw1, sw1, sc1, W16, p0h, p1h, cnt);
  count_kernel<<<(NE + 255) / 256, 256, 0, stream>>>(dst, cnt, slot);
  scan1<<<196, 256, 0, stream>>>(cnt, excl, bsums, NN);
  scan3<<<196, 256, 0, stream>>>(excl, bsums, cnt, row_start, dinv, NN, 196);
  xs_prep<<<(NN * C / 4 + 255) / 256, 256, 0, stream>>>(x, dinv, xs);
  fill_kernel<<<(NE + 255) / 256, 256, 0, stream>>>(src, dst, slot, row_start, csr);
  agg_kernel<<<NN / 4, 256, 0, stream>>>(xs, csr, row_start, dinv, ax16);
  gemmkan<<<(NN + 63) / 64, 256, 0, stream>>>(ax16, W16, gb, p0h, p1h, out);
}

// Round 23
// 140.264 us; speedup vs baseline: 1.1580x; 1.1372x over previous
//
#include <hip/hip_runtime.h>

#define NN 50000
#define NE 800000
#define C 128
#define H 16

typedef unsigned int u32;
typedef unsigned short u16;
typedef __fp16 h2 __attribute__((ext_vector_type(2)));
typedef __fp16 half8 __attribute__((ext_vector_type(8)));
typedef float f32x4 __attribute__((ext_vector_type(4)));

__device__ __forceinline__ h2 as_h2(u32 v) {
  union { u32 u; h2 h; } c; c.u = v; return c.h;
}
__device__ __forceinline__ u32 as_u32(h2 h) {
  union { u32 u; h2 h; } c; c.h = h; return c.u;
}
__device__ __forceinline__ half8 as_half8(uint4 v) {
  union { uint4 u; half8 h; } c; c.u = v; return c.h;
}
#define PK(a, b) __builtin_amdgcn_cvt_pkrtz((a), (b))

// ---------- silu + 7 cubic B-spline bases, closed form, NAMED outputs ----------
__device__ __forceinline__ void feat8s(float x, float& s, float& g0, float& g1,
                                       float& g2, float& g3, float& g4, float& g5,
                                       float& g6) {
  float e = __expf(-x);
  s = x * __builtin_amdgcn_rcpf(1.f + e);
  float t = (x + 2.5f) * 2.0f;
  float cf = floorf(t);
  int c = (int)cf;
  float u = t - cf;
  float u2 = u * u, u3 = u2 * u;
  const float k6 = 1.f / 6.f;
  float P0 = u3 * k6;
  float P1 = (1.f + 3.f * u + 3.f * u2 - 3.f * u3) * k6;
  float P2 = (4.f - 6.f * u2 + 3.f * u3) * k6;
  float om = 1.f - u;
  float P3 = om * om * om * k6;
  bool valid = (t >= 0.f) && (t < 10.f);
#define SPJ(G, J)                                   \
  {                                                 \
    float b = 0.f;                                  \
    b = (c == (J)) ? P0 : b;                        \
    b = (c == (J) + 1) ? P1 : b;                    \
    b = (c == (J) + 2) ? P2 : b;                    \
    b = (c == (J) + 3) ? P3 : b;                    \
    G = valid ? b : 0.f;                            \
  }
  SPJ(g0, 0) SPJ(g1, 1) SPJ(g2, 2) SPJ(g3, 3) SPJ(g4, 4) SPJ(g5, 5) SPJ(g6, 6)
#undef SPJ
}

__device__ __forceinline__ u16 f2bf(float v) {
  u32 b = __float_as_uint(v);
  return (u16)((b + 0x7fffu + ((b >> 16) & 1u)) >> 16);  // RNE
}
__device__ __forceinline__ u16 f2h(float v) {
  union { __fp16 h; u16 u; } c; c.h = (__fp16)v; return c.u;
}
__device__ __forceinline__ float blo(u32 v) { return __uint_as_float(v << 16); }
__device__ __forceinline__ float bhi(u32 v) { return __uint_as_float(v & 0xffff0000u); }

// build a half8 A-fragment from one feat8s evaluation
__device__ __forceinline__ uint4 featfrag(float x) {
  float t0, t1, t2, t3, t4, t5, t6, t7;
  feat8s(x, t0, t1, t2, t3, t4, t5, t6, t7);
  uint4 r;
  r.x = as_u32(PK(t0, t1));
  r.y = as_u32(PK(t2, t3));
  r.z = as_u32(PK(t4, t5));
  r.w = as_u32(PK(t6, t7));
  return r;
}

// ---------- prep_w: weights in MFMA B-FRAGMENT ORDER (step*64 + lane) ----------
// r17-r22 lesson: row-major weights make every B-frag load a 16-line scatter
// (lane rc reads row rc, 2KB stride) -> ~96 latency-exposed loads/wave, the
// invariant stall across all ~50us variants. Fragment order -> 1KB coalesced.
__global__ void prep_w(const float* __restrict__ W,
                       const float* __restrict__ bw0, const float* __restrict__ sw0,
                       const float* __restrict__ sc0,
                       const float* __restrict__ bw1, const float* __restrict__ sw1,
                       const float* __restrict__ sc1,
                       u16* __restrict__ wn, u16* __restrict__ p0n,
                       u16* __restrict__ p1n, int* __restrict__ cnt) {
  int i = blockIdx.x * blockDim.x + threadIdx.x;
  if (i < NN) cnt[i] = 0;
  if (i < 16384) {  // Wn[(t*4+s)*64 + l]*8 + j8  <- W[o=t*16+rc][k=s*32+kb*8+j8]
    int j8 = i & 7, q16 = i >> 3;
    int l = q16 & 63, ts = q16 >> 6;
    int t = ts >> 2, s = ts & 3;
    int rc = l & 15, kb = l >> 4;
    wn[i] = f2h(W[(t * 16 + rc) * C + s * 32 + kb * 8 + j8]);
  }
  if (i < 16384) {  // p0n[s*64 + l]*8 + j8  <- p0[hidden=rc][f=s*4+kb][j8]
    int j8 = i & 7, q16 = i >> 3;
    int l = q16 & 63, s = q16 >> 6;
    int rc = l & 15, kb = l >> 4;
    int of = rc * C + (s * 4 + kb);
    float v = (j8 == 0) ? bw0[of] : sw0[of * 7 + (j8 - 1)] * sc0[of];
    p0n[i] = f2h(v);
  }
  if (i < 16384) {  // p1n[(t*4+ks)*64 + l]*8 + j8 <- p1[o=t*16+rc][hid=ks*4+kb][j8]
    int j8 = i & 7, q16 = i >> 3;
    int l = q16 & 63, tks = q16 >> 6;
    int t = tks >> 2, ks = tks & 3;
    int rc = l & 15, kb = l >> 4;
    int of = (t * 16 + rc) * H + (ks * 4 + kb);
    float v = (j8 == 0) ? bw1[of] : sw1[of * 7 + (j8 - 1)] * sc1[of];
    p1n[i] = f2h(v);
  }
}

// ---------- count + slot capture (u16 slots) ----------
__global__ void count_kernel(const int* __restrict__ dst, int* __restrict__ cnt,
                             u16* __restrict__ slot) {
  int e = blockIdx.x * blockDim.x + threadIdx.x;
  if (e < NE) slot[e] = (u16)atomicAdd(&cnt[dst[e]], 1);
}

// ---------- scan1 ----------
__global__ void scan1(const int* __restrict__ cnt, int* __restrict__ excl,
                      int* __restrict__ bsums, int n) {
  int i = blockIdx.x * 256 + threadIdx.x;
  int v = (i < n) ? cnt[i] : 0;
  int lane = threadIdx.x & 63, wid = threadIdx.x >> 6;
  int s = v;
#pragma unroll
  for (int o = 1; o < 64; o <<= 1) {
    int t = __shfl_up(s, o, 64);
    if (lane >= o) s += t;
  }
  __shared__ int wsum[4];
  if (lane == 63) wsum[wid] = s;
  __syncthreads();
  int woff = 0;
  for (int w = 0; w < wid; ++w) woff += wsum[w];
  if (i < n) excl[i] = woff + s - v;
  if (threadIdx.x == 255) bsums[blockIdx.x] = woff + s;
}

// ---------- scan3 ----------
__global__ void scan3(const int* __restrict__ excl, const int* __restrict__ bsums,
                      const int* __restrict__ cnt, int* __restrict__ row_start,
                      float* __restrict__ dinv, int n, int nb) {
  __shared__ int red[256];
  const int t = threadIdx.x;
  red[t] = (t < nb && t < (int)blockIdx.x) ? bsums[t] : 0;
  __syncthreads();
#pragma unroll
  for (int s = 128; s > 0; s >>= 1) {
    if (t < s) red[t] += red[t + s];
    __syncthreads();
  }
  const int boff = red[0];
  const int i = blockIdx.x * 256 + t;
  if (i < n) {
    row_start[i] = excl[i] + boff;
    dinv[i] = rsqrtf((float)(cnt[i] + 1));
  }
  if (blockIdx.x == 0 && t == 0) row_start[n] = NE;
}

// ---------- xs_prep ----------
__global__ void xs_prep(const float* __restrict__ x, const float* __restrict__ dinv,
                        u32* __restrict__ xs) {
  int i = blockIdx.x * blockDim.x + threadIdx.x;
  if (i < NN * C / 4) {
    int n = i >> 5;
    float dv = dinv[n];
    float4 v = *(const float4*)&x[(size_t)i * 4];
    u32 lo = (u32)f2bf(v.x * dv) | ((u32)f2bf(v.y * dv) << 16);
    u32 hi = (u32)f2bf(v.z * dv) | ((u32)f2bf(v.w * dv) << 16);
    *(uint2*)&xs[(size_t)i * 2] = make_uint2(lo, hi);
  }
}

// ---------- CSR fill: atomic-free 2B scatter ----------
__global__ void fill_kernel(const int* __restrict__ src, const int* __restrict__ dst,
                            const u16* __restrict__ slot,
                            const int* __restrict__ row_start, u16* __restrict__ csr) {
  int e = blockIdx.x * blockDim.x + threadIdx.x;
  if (e < NE) csr[row_start[dst[e]] + (int)slot[e]] = (u16)src[e];
}

// ---------- aggregation (u16 csr stream) ----------
__global__ __launch_bounds__(256, 8) void agg_kernel(
    const u32* __restrict__ xs, const u16* __restrict__ csr,
    const int* __restrict__ row_start, const float* __restrict__ dinv,
    u32* __restrict__ ax16) {
  const int l = threadIdx.x & 63;
  const int node = blockIdx.x * 4 + (threadIdx.x >> 6);
  const int e0 = row_start[node], e1 = row_start[node + 1];
  const float dn = dinv[node];
  const u32 vs = xs[(size_t)node * 64 + l];
  float a0 = blo(vs), a1 = bhi(vs);
  int e = e0;
  for (; e + 8 <= e1; e += 8) {
    const int s0 = csr[e], s1 = csr[e + 1], s2 = csr[e + 2], s3 = csr[e + 3];
    const int s4 = csr[e + 4], s5 = csr[e + 5], s6 = csr[e + 6], s7 = csr[e + 7];
    const u32 v0 = xs[(size_t)s0 * 64 + l];
    const u32 v1 = xs[(size_t)s1 * 64 + l];
    const u32 v2 = xs[(size_t)s2 * 64 + l];
    const u32 v3 = xs[(size_t)s3 * 64 + l];
    const u32 v4 = xs[(size_t)s4 * 64 + l];
    const u32 v5 = xs[(size_t)s5 * 64 + l];
    const u32 v6 = xs[(size_t)s6 * 64 + l];
    const u32 v7 = xs[(size_t)s7 * 64 + l];
    a0 += blo(v0); a1 += bhi(v0);
    a0 += blo(v1); a1 += bhi(v1);
    a0 += blo(v2); a1 += bhi(v2);
    a0 += blo(v3); a1 += bhi(v3);
    a0 += blo(v4); a1 += bhi(v4);
    a0 += blo(v5); a1 += bhi(v5);
    a0 += blo(v6); a1 += bhi(v6);
    a0 += blo(v7); a1 += bhi(v7);
  }
  for (; e < e1; ++e) {
    const u32 v = xs[(size_t)csr[e] * 64 + l];
    a0 += blo(v);
    a1 += bhi(v);
  }
  a0 *= dn;
  a1 *= dn;
  ax16[(size_t)node * 64 + l] = (u32)f2h(a0) | ((u32)f2h(a1) << 16);
}

// ---------- gemmkan v5: coalesced fragment-ordered B loads ----------
// Every B-fragment load = base + l*16B (1KB contiguous per wave).
__global__ __launch_bounds__(256, 3) void gemmkan(
    const u32* __restrict__ ax16, const u16* __restrict__ wn,
    const float* __restrict__ bias, const u16* __restrict__ p0n,
    const u16* __restrict__ p1n, float* __restrict__ out) {
  __shared__ float hT[4][16][132];
  __shared__ float hidT[4][16][17];
  const int wv = threadIdx.x >> 6;
  const int l = threadIdx.x & 63;
  const int m0 = (blockIdx.x * 4 + wv) * 16;
  if (m0 >= NN) return;
  const int rc = l & 15, kb = l >> 4;
  const uint4* Wn4 = (const uint4*)wn;
  const uint4* P0n4 = (const uint4*)p0n;
  const uint4* P1n4 = (const uint4*)p1n;
  // ---- Phase A: GCN GEMM (looped over t) ----
  {
    uint4 a[4];
#pragma unroll
    for (int s = 0; s < 4; ++s)
      a[s] = *(const uint4*)&ax16[(size_t)(m0 + rc) * 64 + s * 16 + kb * 4];
    const int pbase = (rc & 3) * 32 + (rc >> 2);
#pragma unroll 1
    for (int t = 0; t < 8; ++t) {
      f32x4 acc = (f32x4){0.f, 0.f, 0.f, 0.f};
#pragma unroll
      for (int s = 0; s < 4; ++s) {
        uint4 b = Wn4[(t * 4 + s) * 64 + l];
        acc = __builtin_amdgcn_mfma_f32_16x16x32_f16(as_half8(a[s]), as_half8(b),
                                                     acc, 0, 0, 0);
      }
      const float bo = bias[t * 16 + rc];
#pragma unroll
      for (int r = 0; r < 4; ++r) {
        hT[wv][kb * 4 + r][pbase + t * 4] = acc[r] + bo;
      }
    }
  }
  __builtin_amdgcn_s_waitcnt(0);  // wave-local LDS ordering (r17-proven)
  // ---- K0: looped groups of 4 (1 b128 LDS read, 4 featfrags, 4 MFMA) ----
  const float* hrow = &hT[wv][rc][kb * 32];
  f32x4 accA = (f32x4){0.f, 0.f, 0.f, 0.f};
  f32x4 accB = (f32x4){0.f, 0.f, 0.f, 0.f};
#pragma unroll 1
  for (int g = 0; g < 8; ++g) {
    float4 hv = *(const float4*)&hrow[g * 4];
    uint4 f0 = featfrag(hv.x);
    uint4 f1 = featfrag(hv.y);
    uint4 f2 = featfrag(hv.z);
    uint4 f3 = featfrag(hv.w);
    uint4 b0 = P0n4[(g * 4 + 0) * 64 + l];
    uint4 b1 = P0n4[(g * 4 + 1) * 64 + l];
    uint4 b2 = P0n4[(g * 4 + 2) * 64 + l];
    uint4 b3 = P0n4[(g * 4 + 3) * 64 + l];
    accA = __builtin_amdgcn_mfma_f32_16x16x32_f16(as_half8(f0), as_half8(b0), accA, 0, 0, 0);
    accB = __builtin_amdgcn_mfma_f32_16x16x32_f16(as_half8(f1), as_half8(b1), accB, 0, 0, 0);
    accA = __builtin_amdgcn_mfma_f32_16x16x32_f16(as_half8(f2), as_half8(b2), accA, 0, 0, 0);
    accB = __builtin_amdgcn_mfma_f32_16x16x32_f16(as_half8(f3), as_half8(b3), accB, 0, 0, 0);
  }
  f32x4 acc0 = accA + accB;
  // ---- transpose hid within the wave ----
#pragma unroll
  for (int r = 0; r < 4; ++r) hidT[wv][kb * 4 + r][rc] = acc0[r];
  __builtin_amdgcn_s_waitcnt(0);
  // ---- K1 A-fragments (4 independent chains) ----
  uint4 af0 = featfrag(hidT[wv][rc][0 * 4 + kb]);
  uint4 af1 = featfrag(hidT[wv][rc][1 * 4 + kb]);
  uint4 af2 = featfrag(hidT[wv][rc][2 * 4 + kb]);
  uint4 af3 = featfrag(hidT[wv][rc][3 * 4 + kb]);
  // ---- K1: looped over 8 output tiles ----
#pragma unroll 1
  for (int t = 0; t < 8; ++t) {
    uint4 b0 = P1n4[(t * 4 + 0) * 64 + l];
    uint4 b1 = P1n4[(t * 4 + 1) * 64 + l];
    uint4 b2 = P1n4[(t * 4 + 2) * 64 + l];
    uint4 b3 = P1n4[(t * 4 + 3) * 64 + l];
    f32x4 acc1 = (f32x4){0.f, 0.f, 0.f, 0.f};
    acc1 = __builtin_amdgcn_mfma_f32_16x16x32_f16(as_half8(af0), as_half8(b0), acc1, 0, 0, 0);
    acc1 = __builtin_amdgcn_mfma_f32_16x16x32_f16(as_half8(af1), as_half8(b1), acc1, 0, 0, 0);
    acc1 = __builtin_amdgcn_mfma_f32_16x16x32_f16(as_half8(af2), as_half8(b2), acc1, 0, 0, 0);
    acc1 = __builtin_amdgcn_mfma_f32_16x16x32_f16(as_half8(af3), as_half8(b3), acc1, 0, 0, 0);
#pragma unroll
    for (int r = 0; r < 4; ++r) {
      out[(size_t)(m0 + kb * 4 + r) * C + t * 16 + rc] = acc1[r];
    }
  }
}

extern "C" void kernel_launch(void* const* d_in, const int* in_sizes, int n_in,
                              void* d_out, int out_size, void* d_ws, size_t ws_size,
                              hipStream_t stream) {
  const float* x   = (const float*)d_in[0];
  const int*   ei  = (const int*)d_in[1];
  const float* gw  = (const float*)d_in[2];
  const float* gb  = (const float*)d_in[3];
  const float* bw0 = (const float*)d_in[4];
  const float* sw0 = (const float*)d_in[5];
  const float* sc0 = (const float*)d_in[6];
  const float* bw1 = (const float*)d_in[7];
  const float* sw1 = (const float*)d_in[8];
  const float* sc1 = (const float*)d_in[9];
  float* out = (float*)d_out;

  char* p = (char*)d_ws;
  u16* wn = (u16*)p;          p += C * C * 2;            // 32 KB
  u16* p0n = (u16*)p;         p += H * C * 8 * 2;        // 32 KB
  u16* p1n = (u16*)p;         p += C * H * 8 * 2;        // 32 KB
  float* dinv = (float*)p;    p += NN * 4;
  int* cnt = (int*)p;         p += NN * 4;
  int* excl = (int*)p;        p += NN * 4;
  int* bsums = (int*)p;       p += 256 * 4;
  int* row_start = (int*)p;   p += (NN + 4) * 4;
  u16* slot = (u16*)p;        p += (size_t)NE * 2;       // 1.6 MB
  u16* csr = (u16*)p;         p += (size_t)NE * 2;       // 1.6 MB
  p = (char*)(((size_t)p + 15) & ~(size_t)15);
  u32* xs = (u32*)p;          p += (size_t)NN * C * 2;   // 12.8 MB
  u32* ax16 = (u32*)p;        p += (size_t)NN * C * 2;   // 12.8 MB

  const int* src = ei;
  const int* dst = ei + NE;

  prep_w<<<196, 256, 0, stream>>>(gw, bw0, sw0, sc0, bw1, sw1, sc1, wn, p0n, p1n, cnt);
  count_kernel<<<(NE + 255) / 256, 256, 0, stream>>>(dst, cnt, slot);
  scan1<<<196, 256, 0, stream>>>(cnt, excl, bsums, NN);
  scan3<<<196, 256, 0, stream>>>(excl, bsums, cnt, row_start, dinv, NN, 196);
  xs_prep<<<(NN * C / 4 + 255) / 256, 256, 0, stream>>>(x, dinv, xs);
  fill_kernel<<<(NE + 255) / 256, 256, 0, stream>>>(src, dst, slot, row_start, csr);
  agg_kernel<<<NN / 4, 256, 0, stream>>>(xs, csr, row_start, dinv, ax16);
  gemmkan<<<(NN + 63) / 64, 256, 0, stream>>>(ax16, wn, gb, p0n, p1n, out);
}

// Round 24
// 137.589 us; speedup vs baseline: 1.1805x; 1.0194x over previous
//
#include <hip/hip_runtime.h>

#define NN 50000
#define NE 800000
#define C 128
#define H 16

typedef unsigned int u32;
typedef unsigned short u16;
typedef __fp16 h2 __attribute__((ext_vector_type(2)));
typedef __fp16 half8 __attribute__((ext_vector_type(8)));
typedef float f32x4 __attribute__((ext_vector_type(4)));

__device__ __forceinline__ h2 as_h2(u32 v) {
  union { u32 u; h2 h; } c; c.u = v; return c.h;
}
__device__ __forceinline__ u32 as_u32(h2 h) {
  union { u32 u; h2 h; } c; c.h = h; return c.u;
}
__device__ __forceinline__ half8 as_half8(uint4 v) {
  union { uint4 u; half8 h; } c; c.u = v; return c.h;
}
#define PK(a, b) __builtin_amdgcn_cvt_pkrtz((a), (b))

// ---------- silu + 7 cubic B-spline bases, closed form, NAMED outputs ----------
__device__ __forceinline__ void feat8s(float x, float& s, float& g0, float& g1,
                                       float& g2, float& g3, float& g4, float& g5,
                                       float& g6) {
  float e = __expf(-x);
  s = x * __builtin_amdgcn_rcpf(1.f + e);
  float t = (x + 2.5f) * 2.0f;
  float cf = floorf(t);
  int c = (int)cf;
  float u = t - cf;
  float u2 = u * u, u3 = u2 * u;
  const float k6 = 1.f / 6.f;
  float P0 = u3 * k6;
  float P1 = (1.f + 3.f * u + 3.f * u2 - 3.f * u3) * k6;
  float P2 = (4.f - 6.f * u2 + 3.f * u3) * k6;
  float om = 1.f - u;
  float P3 = om * om * om * k6;
  bool valid = (t >= 0.f) && (t < 10.f);
#define SPJ(G, J)                                   \
  {                                                 \
    float b = 0.f;                                  \
    b = (c == (J)) ? P0 : b;                        \
    b = (c == (J) + 1) ? P1 : b;                    \
    b = (c == (J) + 2) ? P2 : b;                    \
    b = (c == (J) + 3) ? P3 : b;                    \
    G = valid ? b : 0.f;                            \
  }
  SPJ(g0, 0) SPJ(g1, 1) SPJ(g2, 2) SPJ(g3, 3) SPJ(g4, 4) SPJ(g5, 5) SPJ(g6, 6)
#undef SPJ
}

__device__ __forceinline__ u16 f2bf(float v) {
  u32 b = __float_as_uint(v);
  return (u16)((b + 0x7fffu + ((b >> 16) & 1u)) >> 16);  // RNE
}
__device__ __forceinline__ u16 f2h(float v) {
  union { __fp16 h; u16 u; } c; c.h = (__fp16)v; return c.u;
}
__device__ __forceinline__ float blo(u32 v) { return __uint_as_float(v << 16); }
__device__ __forceinline__ float bhi(u32 v) { return __uint_as_float(v & 0xffff0000u); }

// build a half8 A-fragment from one feat8s evaluation
__device__ __forceinline__ uint4 featfrag(float x) {
  float t0, t1, t2, t3, t4, t5, t6, t7;
  feat8s(x, t0, t1, t2, t3, t4, t5, t6, t7);
  uint4 r;
  r.x = as_u32(PK(t0, t1));
  r.y = as_u32(PK(t2, t3));
  r.z = as_u32(PK(t4, t5));
  r.w = as_u32(PK(t6, t7));
  return r;
}

// ---------- prep_w: weights in MFMA B-FRAGMENT ORDER (step*64 + lane) ----------
__global__ void prep_w(const float* __restrict__ W,
                       const float* __restrict__ bw0, const float* __restrict__ sw0,
                       const float* __restrict__ sc0,
                       const float* __restrict__ bw1, const float* __restrict__ sw1,
                       const float* __restrict__ sc1,
                       u16* __restrict__ wn, u16* __restrict__ p0n,
                       u16* __restrict__ p1n, int* __restrict__ cnt) {
  int i = blockIdx.x * blockDim.x + threadIdx.x;
  if (i < NN) cnt[i] = 0;
  if (i < 16384) {  // Wn[(t*4+s)*64 + l]*8 + j8  <- W[o=t*16+rc][k=s*32+kb*8+j8]
    int j8 = i & 7, q16 = i >> 3;
    int l = q16 & 63, ts = q16 >> 6;
    int t = ts >> 2, s = ts & 3;
    int rc = l & 15, kb = l >> 4;
    wn[i] = f2h(W[(t * 16 + rc) * C + s * 32 + kb * 8 + j8]);
  }
  if (i < 16384) {  // p0n[s*64 + l]*8 + j8  <- p0[hidden=rc][f=s*4+kb][j8]
    int j8 = i & 7, q16 = i >> 3;
    int l = q16 & 63, s = q16 >> 6;
    int rc = l & 15, kb = l >> 4;
    int of = rc * C + (s * 4 + kb);
    float v = (j8 == 0) ? bw0[of] : sw0[of * 7 + (j8 - 1)] * sc0[of];
    p0n[i] = f2h(v);
  }
  if (i < 16384) {  // p1n[(t*4+ks)*64 + l]*8 + j8 <- p1[o=t*16+rc][hid=ks*4+kb][j8]
    int j8 = i & 7, q16 = i >> 3;
    int l = q16 & 63, tks = q16 >> 6;
    int t = tks >> 2, ks = tks & 3;
    int rc = l & 15, kb = l >> 4;
    int of = (t * 16 + rc) * H + (ks * 4 + kb);
    float v = (j8 == 0) ? bw1[of] : sw1[of * 7 + (j8 - 1)] * sc1[of];
    p1n[i] = f2h(v);
  }
}

// ---------- count + slot capture (u16 slots) ----------
__global__ void count_kernel(const int* __restrict__ dst, int* __restrict__ cnt,
                             u16* __restrict__ slot) {
  int e = blockIdx.x * blockDim.x + threadIdx.x;
  if (e < NE) slot[e] = (u16)atomicAdd(&cnt[dst[e]], 1);
}

// ---------- scan1 ----------
__global__ void scan1(const int* __restrict__ cnt, int* __restrict__ excl,
                      int* __restrict__ bsums, int n) {
  int i = blockIdx.x * 256 + threadIdx.x;
  int v = (i < n) ? cnt[i] : 0;
  int lane = threadIdx.x & 63, wid = threadIdx.x >> 6;
  int s = v;
#pragma unroll
  for (int o = 1; o < 64; o <<= 1) {
    int t = __shfl_up(s, o, 64);
    if (lane >= o) s += t;
  }
  __shared__ int wsum[4];
  if (lane == 63) wsum[wid] = s;
  __syncthreads();
  int woff = 0;
  for (int w = 0; w < wid; ++w) woff += wsum[w];
  if (i < n) excl[i] = woff + s - v;
  if (threadIdx.x == 255) bsums[blockIdx.x] = woff + s;
}

// ---------- scan3 ----------
__global__ void scan3(const int* __restrict__ excl, const int* __restrict__ bsums,
                      const int* __restrict__ cnt, int* __restrict__ row_start,
                      float* __restrict__ dinv, int n, int nb) {
  __shared__ int red[256];
  const int t = threadIdx.x;
  red[t] = (t < nb && t < (int)blockIdx.x) ? bsums[t] : 0;
  __syncthreads();
#pragma unroll
  for (int s = 128; s > 0; s >>= 1) {
    if (t < s) red[t] += red[t + s];
    __syncthreads();
  }
  const int boff = red[0];
  const int i = blockIdx.x * 256 + t;
  if (i < n) {
    row_start[i] = excl[i] + boff;
    dinv[i] = rsqrtf((float)(cnt[i] + 1));
  }
  if (blockIdx.x == 0 && t == 0) row_start[n] = NE;
}

// ---------- fillxs: CSR fill + xs build (merged; both depend only on scan3) ----------
__global__ void fillxs(const int* __restrict__ src, const int* __restrict__ dst,
                       const u16* __restrict__ slot, const int* __restrict__ row_start,
                       const float* __restrict__ x, const float* __restrict__ dinv,
                       u16* __restrict__ csr, u32* __restrict__ xs) {
  int i = blockIdx.x * blockDim.x + threadIdx.x;
  if (i < NE) csr[row_start[dst[i]] + (int)slot[i]] = (u16)src[i];
  if (i < NN * C / 4) {
    int n = i >> 5;
    float dv = dinv[n];
    float4 v = *(const float4*)&x[(size_t)i * 4];
    u32 lo = (u32)f2bf(v.x * dv) | ((u32)f2bf(v.y * dv) << 16);
    u32 hi = (u32)f2bf(v.z * dv) | ((u32)f2bf(v.w * dv) << 16);
    *(uint2*)&xs[(size_t)i * 2] = make_uint2(lo, hi);
  }
}

// ---------- aggregation (u16 csr stream) ----------
__global__ __launch_bounds__(256, 8) void agg_kernel(
    const u32* __restrict__ xs, const u16* __restrict__ csr,
    const int* __restrict__ row_start, const float* __restrict__ dinv,
    u32* __restrict__ ax16) {
  const int l = threadIdx.x & 63;
  const int node = blockIdx.x * 4 + (threadIdx.x >> 6);
  const int e0 = row_start[node], e1 = row_start[node + 1];
  const float dn = dinv[node];
  const u32 vs = xs[(size_t)node * 64 + l];
  float a0 = blo(vs), a1 = bhi(vs);
  int e = e0;
  for (; e + 8 <= e1; e += 8) {
    const int s0 = csr[e], s1 = csr[e + 1], s2 = csr[e + 2], s3 = csr[e + 3];
    const int s4 = csr[e + 4], s5 = csr[e + 5], s6 = csr[e + 6], s7 = csr[e + 7];
    const u32 v0 = xs[(size_t)s0 * 64 + l];
    const u32 v1 = xs[(size_t)s1 * 64 + l];
    const u32 v2 = xs[(size_t)s2 * 64 + l];
    const u32 v3 = xs[(size_t)s3 * 64 + l];
    const u32 v4 = xs[(size_t)s4 * 64 + l];
    const u32 v5 = xs[(size_t)s5 * 64 + l];
    const u32 v6 = xs[(size_t)s6 * 64 + l];
    const u32 v7 = xs[(size_t)s7 * 64 + l];
    a0 += blo(v0); a1 += bhi(v0);
    a0 += blo(v1); a1 += bhi(v1);
    a0 += blo(v2); a1 += bhi(v2);
    a0 += blo(v3); a1 += bhi(v3);
    a0 += blo(v4); a1 += bhi(v4);
    a0 += blo(v5); a1 += bhi(v5);
    a0 += blo(v6); a1 += bhi(v6);
    a0 += blo(v7); a1 += bhi(v7);
  }
  for (; e < e1; ++e) {
    const u32 v = xs[(size_t)csr[e] * 64 + l];
    a0 += blo(v);
    a1 += bhi(v);
  }
  a0 *= dn;
  a1 *= dn;
  ax16[(size_t)node * 64 + l] = (u32)f2h(a0) | ((u32)f2h(a1) << 16);
}

// ---------- gemmkan v6: software-pipelined loads (double-buffer every loop) ----------
// r23: fragment-order B made loads regular; unroll-1 loops still serialize
// {load -> featfrag -> MFMA}. Prefetch iter g+1's h-tile + B-frags while
// computing iter g.
__global__ __launch_bounds__(256, 3) void gemmkan(
    const u32* __restrict__ ax16, const u16* __restrict__ wn,
    const float* __restrict__ bias, const u16* __restrict__ p0n,
    const u16* __restrict__ p1n, float* __restrict__ out) {
  __shared__ float hT[4][16][132];
  __shared__ float hidT[4][16][17];
  const int wv = threadIdx.x >> 6;
  const int l = threadIdx.x & 63;
  const int m0 = (blockIdx.x * 4 + wv) * 16;
  if (m0 >= NN) return;
  const int rc = l & 15, kb = l >> 4;
  const uint4* Wn4 = (const uint4*)wn;
  const uint4* P0n4 = (const uint4*)p0n;
  const uint4* P1n4 = (const uint4*)p1n;
  // ---- Phase A: GCN GEMM, pipelined over t ----
  {
    uint4 a[4];
#pragma unroll
    for (int s = 0; s < 4; ++s)
      a[s] = *(const uint4*)&ax16[(size_t)(m0 + rc) * 64 + s * 16 + kb * 4];
    const int pbase = (rc & 3) * 32 + (rc >> 2);
    uint4 bc0 = Wn4[0 * 64 + l], bc1 = Wn4[1 * 64 + l];
    uint4 bc2 = Wn4[2 * 64 + l], bc3 = Wn4[3 * 64 + l];
#pragma unroll 1
    for (int t = 0; t < 8; ++t) {
      const int tn = (t + 1) & 7;
      uint4 bn0 = Wn4[(tn * 4 + 0) * 64 + l];
      uint4 bn1 = Wn4[(tn * 4 + 1) * 64 + l];
      uint4 bn2 = Wn4[(tn * 4 + 2) * 64 + l];
      uint4 bn3 = Wn4[(tn * 4 + 3) * 64 + l];
      f32x4 acc = (f32x4){0.f, 0.f, 0.f, 0.f};
      acc = __builtin_amdgcn_mfma_f32_16x16x32_f16(as_half8(a[0]), as_half8(bc0), acc, 0, 0, 0);
      acc = __builtin_amdgcn_mfma_f32_16x16x32_f16(as_half8(a[1]), as_half8(bc1), acc, 0, 0, 0);
      acc = __builtin_amdgcn_mfma_f32_16x16x32_f16(as_half8(a[2]), as_half8(bc2), acc, 0, 0, 0);
      acc = __builtin_amdgcn_mfma_f32_16x16x32_f16(as_half8(a[3]), as_half8(bc3), acc, 0, 0, 0);
      const float bo = bias[t * 16 + rc];
#pragma unroll
      for (int r = 0; r < 4; ++r) {
        hT[wv][kb * 4 + r][pbase + t * 4] = acc[r] + bo;
      }
      bc0 = bn0; bc1 = bn1; bc2 = bn2; bc3 = bn3;
    }
  }
  __builtin_amdgcn_s_waitcnt(0);  // wave-local LDS ordering (r17-proven)
  // ---- K0: pipelined groups of 4 ----
  const float* hrow = &hT[wv][rc][kb * 32];
  f32x4 accA = (f32x4){0.f, 0.f, 0.f, 0.f};
  f32x4 accB = (f32x4){0.f, 0.f, 0.f, 0.f};
  {
    float4 hv = *(const float4*)&hrow[0];
    uint4 bc0 = P0n4[0 * 64 + l], bc1 = P0n4[1 * 64 + l];
    uint4 bc2 = P0n4[2 * 64 + l], bc3 = P0n4[3 * 64 + l];
#pragma unroll 1
    for (int g = 0; g < 8; ++g) {
      const int gn = (g + 1) & 7;
      float4 hv_n = *(const float4*)&hrow[gn * 4];
      uint4 bn0 = P0n4[(gn * 4 + 0) * 64 + l];
      uint4 bn1 = P0n4[(gn * 4 + 1) * 64 + l];
      uint4 bn2 = P0n4[(gn * 4 + 2) * 64 + l];
      uint4 bn3 = P0n4[(gn * 4 + 3) * 64 + l];
      uint4 f0 = featfrag(hv.x);
      uint4 f1 = featfrag(hv.y);
      uint4 f2 = featfrag(hv.z);
      uint4 f3 = featfrag(hv.w);
      accA = __builtin_amdgcn_mfma_f32_16x16x32_f16(as_half8(f0), as_half8(bc0), accA, 0, 0, 0);
      accB = __builtin_amdgcn_mfma_f32_16x16x32_f16(as_half8(f1), as_half8(bc1), accB, 0, 0, 0);
      accA = __builtin_amdgcn_mfma_f32_16x16x32_f16(as_half8(f2), as_half8(bc2), accA, 0, 0, 0);
      accB = __builtin_amdgcn_mfma_f32_16x16x32_f16(as_half8(f3), as_half8(bc3), accB, 0, 0, 0);
      hv = hv_n;
      bc0 = bn0; bc1 = bn1; bc2 = bn2; bc3 = bn3;
    }
  }
  f32x4 acc0 = accA + accB;
  // ---- transpose hid within the wave ----
#pragma unroll
  for (int r = 0; r < 4; ++r) hidT[wv][kb * 4 + r][rc] = acc0[r];
  __builtin_amdgcn_s_waitcnt(0);
  // ---- K1 A-fragments (4 independent chains) ----
  uint4 af0 = featfrag(hidT[wv][rc][0 * 4 + kb]);
  uint4 af1 = featfrag(hidT[wv][rc][1 * 4 + kb]);
  uint4 af2 = featfrag(hidT[wv][rc][2 * 4 + kb]);
  uint4 af3 = featfrag(hidT[wv][rc][3 * 4 + kb]);
  // ---- K1: pipelined over 8 output tiles ----
  {
    uint4 bc0 = P1n4[0 * 64 + l], bc1 = P1n4[1 * 64 + l];
    uint4 bc2 = P1n4[2 * 64 + l], bc3 = P1n4[3 * 64 + l];
#pragma unroll 1
    for (int t = 0; t < 8; ++t) {
      const int tn = (t + 1) & 7;
      uint4 bn0 = P1n4[(tn * 4 + 0) * 64 + l];
      uint4 bn1 = P1n4[(tn * 4 + 1) * 64 + l];
      uint4 bn2 = P1n4[(tn * 4 + 2) * 64 + l];
      uint4 bn3 = P1n4[(tn * 4 + 3) * 64 + l];
      f32x4 acc1 = (f32x4){0.f, 0.f, 0.f, 0.f};
      acc1 = __builtin_amdgcn_mfma_f32_16x16x32_f16(as_half8(af0), as_half8(bc0), acc1, 0, 0, 0);
      acc1 = __builtin_amdgcn_mfma_f32_16x16x32_f16(as_half8(af1), as_half8(bc1), acc1, 0, 0, 0);
      acc1 = __builtin_amdgcn_mfma_f32_16x16x32_f16(as_half8(af2), as_half8(bc2), acc1, 0, 0, 0);
      acc1 = __builtin_amdgcn_mfma_f32_16x16x32_f16(as_half8(af3), as_half8(bc3), acc1, 0, 0, 0);
#pragma unroll
      for (int r = 0; r < 4; ++r) {
        out[(size_t)(m0 + kb * 4 + r) * C + t * 16 + rc] = acc1[r];
      }
      bc0 = bn0; bc1 = bn1; bc2 = bn2; bc3 = bn3;
    }
  }
}

extern "C" void kernel_launch(void* const* d_in, const int* in_sizes, int n_in,
                              void* d_out, int out_size, void* d_ws, size_t ws_size,
                              hipStream_t stream) {
  const float* x   = (const float*)d_in[0];
  const int*   ei  = (const int*)d_in[1];
  const float* gw  = (const float*)d_in[2];
  const float* gb  = (const float*)d_in[3];
  const float* bw0 = (const float*)d_in[4];
  const float* sw0 = (const float*)d_in[5];
  const float* sc0 = (const float*)d_in[6];
  const float* bw1 = (const float*)d_in[7];
  const float* sw1 = (const float*)d_in[8];
  const float* sc1 = (const float*)d_in[9];
  float* out = (float*)d_out;

  char* p = (char*)d_ws;
  u16* wn = (u16*)p;          p += C * C * 2;            // 32 KB
  u16* p0n = (u16*)p;         p += H * C * 8 * 2;        // 32 KB
  u16* p1n = (u16*)p;         p += C * H * 8 * 2;        // 32 KB
  float* dinv = (float*)p;    p += NN * 4;
  int* cnt = (int*)p;         p += NN * 4;
  int* excl = (int*)p;        p += NN * 4;
  int* bsums = (int*)p;       p += 256 * 4;
  int* row_start = (int*)p;   p += (NN + 4) * 4;
  u16* slot = (u16*)p;        p += (size_t)NE * 2;       // 1.6 MB
  u16* csr = (u16*)p;         p += (size_t)NE * 2;       // 1.6 MB
  p = (char*)(((size_t)p + 15) & ~(size_t)15);
  u32* xs = (u32*)p;          p += (size_t)NN * C * 2;   // 12.8 MB
  u32* ax16 = (u32*)p;        p += (size_t)NN * C * 2;   // 12.8 MB

  const int* src = ei;
  const int* dst = ei + NE;

  prep_w<<<196, 256, 0, stream>>>(gw, bw0, sw0, sc0, bw1, sw1, sc1, wn, p0n, p1n, cnt);
  count_kernel<<<(NE + 255) / 256, 256, 0, stream>>>(dst, cnt, slot);
  scan1<<<196, 256, 0, stream>>>(cnt, excl, bsums, NN);
  scan3<<<196, 256, 0, stream>>>(excl, bsums, cnt, row_start, dinv, NN, 196);
  fillxs<<<(NN * C / 4 + 255) / 256, 256, 0, stream>>>(src, dst, slot, row_start,
                                                       x, dinv, csr, xs);
  agg_kernel<<<NN / 4, 256, 0, stream>>>(xs, csr, row_start, dinv, ax16);
  gemmkan<<<(NN + 63) / 64, 256, 0, stream>>>(ax16, wn, gb, p0n, p1n, out);
}